// Round 2
// baseline (5871.590 us; speedup 1.0000x reference)
//
#include <hip/hip_runtime.h>

#define N_NODES 100000
#define IN_DIM  256
#define HID_DIM 128
#define OUT_DIM 237

// ---------------- degree / dinv ----------------
__global__ void k_deg(const int* __restrict__ dst, float* __restrict__ deg, int E) {
    int e = blockIdx.x * 256 + threadIdx.x;
    if (e < E) atomicAdd(&deg[dst[e]], 1.0f);
}

__global__ void k_dinv(float* __restrict__ deg, int n) {
    int i = blockIdx.x * 256 + threadIdx.x;
    if (i < n) deg[i] = rsqrtf(deg[i] + 1.0f);  // +1 self-loop; always > 0
}

// ---------------- GEMM1: hs = (X @ W1) * dinv[row] ----------------
// X [N,256], W1 [256,128]. Tile 64x64, BK=16, 256 threads, 4x4 micro-tile.
__global__ __launch_bounds__(256) void k_gemm1(const float* __restrict__ X,
                                               const float* __restrict__ W,
                                               const float* __restrict__ dinv,
                                               float* __restrict__ out) {
    __shared__ float As[16 * 68];   // [k][row], stride 68
    __shared__ float Bs[16 * 64];   // [k][col]
    const int tid = threadIdx.x;
    const int tx = tid & 15, ty = tid >> 4;
    const int row0 = blockIdx.x * 64;
    const int col0 = blockIdx.y * 64;

    const int ar = tid >> 2;          // 0..63 tile row (A stage)
    const int ak = (tid & 3) * 4;     // k offset, float4
    const int bk = tid >> 4;          // 0..15 k row (B stage)
    const int bc = (tid & 15) * 4;    // col offset, float4

    float acc[4][4] = {};

    for (int k0 = 0; k0 < IN_DIM; k0 += 16) {
        float4 a4 = make_float4(0.f, 0.f, 0.f, 0.f);
        const int grow = row0 + ar;
        if (grow < N_NODES) a4 = *(const float4*)(X + (size_t)grow * IN_DIM + k0 + ak);
        float4 b4 = *(const float4*)(W + (size_t)(k0 + bk) * HID_DIM + col0 + bc);
        __syncthreads();
        As[(ak + 0) * 68 + ar] = a4.x;
        As[(ak + 1) * 68 + ar] = a4.y;
        As[(ak + 2) * 68 + ar] = a4.z;
        As[(ak + 3) * 68 + ar] = a4.w;
        *(float4*)(Bs + bk * 64 + bc) = b4;
        __syncthreads();
#pragma unroll
        for (int kk = 0; kk < 16; ++kk) {
            float4 av = *(const float4*)(As + kk * 68 + ty * 4);
            float4 bv = *(const float4*)(Bs + kk * 64 + tx * 4);
            float a_[4] = {av.x, av.y, av.z, av.w};
            float b_[4] = {bv.x, bv.y, bv.z, bv.w};
#pragma unroll
            for (int i = 0; i < 4; ++i)
#pragma unroll
                for (int j = 0; j < 4; ++j)
                    acc[i][j] = fmaf(a_[i], b_[j], acc[i][j]);
        }
    }
#pragma unroll
    for (int i = 0; i < 4; ++i) {
        const int r = row0 + ty * 4 + i;
        if (r < N_NODES) {
            const float s = dinv[r];
            float4 v = make_float4(acc[i][0] * s, acc[i][1] * s, acc[i][2] * s, acc[i][3] * s);
            *(float4*)(out + (size_t)r * HID_DIM + col0 + tx * 4) = v;
        }
    }
}

// ---------------- edge aggregation: agg[dst] += hs[src] (128 dims) ----------------
__global__ void k_agg(const float* __restrict__ hs, const int* __restrict__ src,
                      const int* __restrict__ dst, float* __restrict__ agg, int E) {
    int t = blockIdx.x * 256 + threadIdx.x;
    int e = t >> 5;
    int q = (t & 31) * 4;
    if (e < E) {
        int s = src[e], d = dst[e];
        float4 v = *(const float4*)(hs + (size_t)s * HID_DIM + q);
        float* o = agg + (size_t)d * HID_DIM + q;
        atomicAdd(o + 0, v.x);
        atomicAdd(o + 1, v.y);
        atomicAdd(o + 2, v.z);
        atomicAdd(o + 3, v.w);
    }
}

// ---- epilogue 1: h = relu(dinv*(agg+hs)+b1); hs <- h*dinv (in place); agg untouched ----
__global__ void k_epi1(float* __restrict__ hs, const float* __restrict__ agg,
                       const float* __restrict__ dinv, const float* __restrict__ b1, int n) {
    int t = blockIdx.x * 256 + threadIdx.x;
    if (t < n * 32) {
        int r = t >> 5, q = (t & 31) * 4;
        float s = dinv[r];
        float4 a = *(const float4*)(agg + (size_t)r * HID_DIM + q);
        float4 h0 = *(const float4*)(hs + (size_t)r * HID_DIM + q);
        float4 bb = *(const float4*)(b1 + q);
        float4 h;
        h.x = fmaxf(fmaf(s, a.x + h0.x, bb.x), 0.f) * s;
        h.y = fmaxf(fmaf(s, a.y + h0.y, bb.y), 0.f) * s;
        h.z = fmaxf(fmaf(s, a.z + h0.z, bb.z), 0.f) * s;
        h.w = fmaxf(fmaf(s, a.w + h0.w, bb.w), 0.f) * s;
        *(float4*)(hs + (size_t)r * HID_DIM + q) = h;
    }
}

// ---- epilogue 2: agg <- dinv*(agg + hs) (in place). Frees hs (d_out) for GEMM2. ----
__global__ void k_epi2(float* __restrict__ agg, const float* __restrict__ hs,
                       const float* __restrict__ dinv, int n) {
    int t = blockIdx.x * 256 + threadIdx.x;
    if (t < n * 32) {
        int r = t >> 5, q = (t & 31) * 4;
        float s = dinv[r];
        float4 a = *(const float4*)(agg + (size_t)r * HID_DIM + q);
        float4 h = *(const float4*)(hs + (size_t)r * HID_DIM + q);
        float4 v = make_float4(s * (a.x + h.x), s * (a.y + h.y), s * (a.z + h.z), s * (a.w + h.w));
        *(float4*)(agg + (size_t)r * HID_DIM + q) = v;
    }
}

// ---------------- GEMM2: out = A2 @ W2 + b2,  A2 = agg [N,128] ----------------
__global__ __launch_bounds__(256) void k_gemm2(const float* __restrict__ A2,
                                               const float* __restrict__ W2,
                                               const float* __restrict__ b2,
                                               float* __restrict__ out) {
    __shared__ float As[16 * 68];
    __shared__ float Bs[16 * 64];
    const int tid = threadIdx.x;
    const int tx = tid & 15, ty = tid >> 4;
    const int row0 = blockIdx.x * 64;
    const int col0 = blockIdx.y * 64;

    const int ar = tid >> 2;
    const int ak = (tid & 3) * 4;
    const int bk = tid >> 4;
    const int bc = (tid & 15) * 4;

    float acc[4][4] = {};

    for (int k0 = 0; k0 < HID_DIM; k0 += 16) {
        float4 a4 = make_float4(0.f, 0.f, 0.f, 0.f);
        const int grow = row0 + ar;
        if (grow < N_NODES) a4 = *(const float4*)(A2 + (size_t)grow * HID_DIM + k0 + ak);
        float bv[4];
#pragma unroll
        for (int j = 0; j < 4; ++j) {
            int c = col0 + bc + j;
            bv[j] = (c < OUT_DIM) ? W2[(size_t)(k0 + bk) * OUT_DIM + c] : 0.f;
        }
        __syncthreads();
        As[(ak + 0) * 68 + ar] = a4.x;
        As[(ak + 1) * 68 + ar] = a4.y;
        As[(ak + 2) * 68 + ar] = a4.z;
        As[(ak + 3) * 68 + ar] = a4.w;
        Bs[bk * 64 + bc + 0] = bv[0];
        Bs[bk * 64 + bc + 1] = bv[1];
        Bs[bk * 64 + bc + 2] = bv[2];
        Bs[bk * 64 + bc + 3] = bv[3];
        __syncthreads();
#pragma unroll
        for (int kk = 0; kk < 16; ++kk) {
            float4 av = *(const float4*)(As + kk * 68 + ty * 4);
            float4 bv4 = *(const float4*)(Bs + kk * 64 + tx * 4);
            float a_[4] = {av.x, av.y, av.z, av.w};
            float b_[4] = {bv4.x, bv4.y, bv4.z, bv4.w};
#pragma unroll
            for (int i = 0; i < 4; ++i)
#pragma unroll
                for (int j = 0; j < 4; ++j)
                    acc[i][j] = fmaf(a_[i], b_[j], acc[i][j]);
        }
    }
#pragma unroll
    for (int i = 0; i < 4; ++i) {
        const int r = row0 + ty * 4 + i;
        if (r < N_NODES) {
#pragma unroll
            for (int j = 0; j < 4; ++j) {
                int c = col0 + tx * 4 + j;
                if (c < OUT_DIM) out[(size_t)r * OUT_DIM + c] = acc[i][j] + b2[c];
            }
        }
    }
}

extern "C" void kernel_launch(void* const* d_in, const int* in_sizes, int n_in,
                              void* d_out, int out_size, void* d_ws, size_t ws_size,
                              hipStream_t stream) {
    const float* x  = (const float*)d_in[0];
    const int*   ei = (const int*)d_in[1];
    const float* W1 = (const float*)d_in[2];
    const float* b1 = (const float*)d_in[3];
    const float* W2 = (const float*)d_in[4];
    const float* b2 = (const float*)d_in[5];
    float* out = (float*)d_out;

    const int E = in_sizes[1] / 2;
    const int* src = ei;
    const int* dst = ei + E;

    // Workspace: deg/dinv (N floats) + agg (N*128 floats)  ~= 51.7 MB
    char* ws = (char*)d_ws;
    float* deg = (float*)ws;
    size_t off = ((size_t)N_NODES * 4 + 255) / 256 * 256;
    float* agg = (float*)(ws + off);
    // hs lives inside d_out (needs N*128 floats = 51.2 MB < out 94.8 MB).
    // All readers of hs complete before k_gemm2 writes d_out (stream order).
    float* hs = out;

    hipMemsetAsync(deg, 0, (size_t)N_NODES * 4, stream);
    k_deg<<<(E + 255) / 256, 256, 0, stream>>>(dst, deg, E);
    k_dinv<<<(N_NODES + 255) / 256, 256, 0, stream>>>(deg, N_NODES);

    dim3 g1((N_NODES + 63) / 64, HID_DIM / 64);
    k_gemm1<<<g1, 256, 0, stream>>>(x, W1, deg, hs);

    hipMemsetAsync(agg, 0, (size_t)N_NODES * HID_DIM * 4, stream);
    {
        long long nt = (long long)E * 32;
        k_agg<<<(unsigned)((nt + 255) / 256), 256, 0, stream>>>(hs, src, dst, agg, E);
    }
    k_epi1<<<(N_NODES * 32 + 255) / 256, 256, 0, stream>>>(hs, agg, deg, b1, N_NODES);

    hipMemsetAsync(agg, 0, (size_t)N_NODES * HID_DIM * 4, stream);
    {
        long long nt = (long long)E * 32;
        k_agg<<<(unsigned)((nt + 255) / 256), 256, 0, stream>>>(hs, src, dst, agg, E);
    }
    k_epi2<<<(N_NODES * 32 + 255) / 256, 256, 0, stream>>>(agg, hs, deg, N_NODES);

    dim3 g2((N_NODES + 63) / 64, (OUT_DIM + 63) / 64);
    k_gemm2<<<g2, 256, 0, stream>>>(agg, W2, b2, out);
}

// Round 3
// 781.044 us; speedup vs baseline: 7.5176x; 7.5176x over previous
//
#include <hip/hip_runtime.h>

#define N_NODES 100000
#define IN_DIM  256
#define HID_DIM 128
#define OUT_DIM 237

// ---------------- degree histogram (int) ----------------
__global__ void k_deg(const int* __restrict__ dst, int* __restrict__ cnt, int E) {
    int e = blockIdx.x * 256 + threadIdx.x;
    if (e < E) atomicAdd(&cnt[dst[e]], 1);
}

__global__ void k_dinv(const int* __restrict__ cnt, float* __restrict__ dinv, int n) {
    int i = blockIdx.x * 256 + threadIdx.x;
    if (i < n) dinv[i] = rsqrtf((float)cnt[i] + 1.0f);  // +1 self-loop
}

// ---------------- 2-level exclusive scan over cnt[0..n) ----------------
// scan1: per-block (1024 elems) exclusive scan -> rp, block total -> bsum
__global__ __launch_bounds__(256) void k_scan1(const int* __restrict__ cnt,
                                               int* __restrict__ rp,
                                               int* __restrict__ bsum, int n) {
    __shared__ int lds[256];
    const int tid = threadIdx.x;
    const int base = blockIdx.x * 1024 + tid * 4;
    int v[4];
#pragma unroll
    for (int j = 0; j < 4; ++j) v[j] = (base + j < n) ? cnt[base + j] : 0;
    int s = v[0] + v[1] + v[2] + v[3];
    lds[tid] = s;
    __syncthreads();
    for (int off = 1; off < 256; off <<= 1) {
        int t = (tid >= off) ? lds[tid - off] : 0;
        __syncthreads();
        lds[tid] += t;
        __syncthreads();
    }
    int excl = lds[tid] - s;
    int run = excl;
#pragma unroll
    for (int j = 0; j < 4; ++j) {
        if (base + j < n) rp[base + j] = run;
        run += v[j];
    }
    if (tid == 255) bsum[blockIdx.x] = lds[255];
}

// scan2: exclusive scan of block sums (nb <= 128), 1 block of 128 threads
__global__ void k_scan2(int* __restrict__ bsum, int nb) {
    __shared__ int lds[128];
    int tid = threadIdx.x;
    int v = (tid < nb) ? bsum[tid] : 0;
    lds[tid] = v;
    __syncthreads();
    for (int off = 1; off < 128; off <<= 1) {
        int t = (tid >= off) ? lds[tid - off] : 0;
        __syncthreads();
        lds[tid] += t;
        __syncthreads();
    }
    if (tid < nb) bsum[tid] = lds[tid] - v;
}

// scan3: rp += bsum[b]; fill = rp (scatter cursors); rp[n] = E
__global__ __launch_bounds__(256) void k_scan3(int* __restrict__ rp, int* __restrict__ fill,
                                               const int* __restrict__ bsum, int n, int E) {
    const int tid = threadIdx.x;
    const int base = blockIdx.x * 1024 + tid * 4;
    const int add = bsum[blockIdx.x];
#pragma unroll
    for (int j = 0; j < 4; ++j) {
        int i = base + j;
        if (i < n) {
            int v = rp[i] + add;
            rp[i] = v;
            fill[i] = v;
        }
    }
    if (blockIdx.x == 0 && tid == 0) rp[n] = E;
}

// scatter edges into dst-sorted order (order within a node irrelevant for sum)
__global__ void k_scatter(const int* __restrict__ src, const int* __restrict__ dst,
                          int* __restrict__ fill, int* __restrict__ ss, int E) {
    int e = blockIdx.x * 256 + threadIdx.x;
    if (e < E) {
        int d = dst[e];
        int pos = atomicAdd(&fill[d], 1);
        ss[pos] = src[e];
    }
}

// ---------------- GEMM1: hs = (X @ W1) * dinv[row] ----------------
__global__ __launch_bounds__(256) void k_gemm1(const float* __restrict__ X,
                                               const float* __restrict__ W,
                                               const float* __restrict__ dinv,
                                               float* __restrict__ out) {
    __shared__ float As[16 * 68];
    __shared__ float Bs[16 * 64];
    const int tid = threadIdx.x;
    const int tx = tid & 15, ty = tid >> 4;
    const int row0 = blockIdx.x * 64;
    const int col0 = blockIdx.y * 64;

    const int ar = tid >> 2;
    const int ak = (tid & 3) * 4;
    const int bk = tid >> 4;
    const int bc = (tid & 15) * 4;

    float acc[4][4] = {};

    for (int k0 = 0; k0 < IN_DIM; k0 += 16) {
        float4 a4 = make_float4(0.f, 0.f, 0.f, 0.f);
        const int grow = row0 + ar;
        if (grow < N_NODES) a4 = *(const float4*)(X + (size_t)grow * IN_DIM + k0 + ak);
        float4 b4 = *(const float4*)(W + (size_t)(k0 + bk) * HID_DIM + col0 + bc);
        __syncthreads();
        As[(ak + 0) * 68 + ar] = a4.x;
        As[(ak + 1) * 68 + ar] = a4.y;
        As[(ak + 2) * 68 + ar] = a4.z;
        As[(ak + 3) * 68 + ar] = a4.w;
        *(float4*)(Bs + bk * 64 + bc) = b4;
        __syncthreads();
#pragma unroll
        for (int kk = 0; kk < 16; ++kk) {
            float4 av = *(const float4*)(As + kk * 68 + ty * 4);
            float4 bv = *(const float4*)(Bs + kk * 64 + tx * 4);
            float a_[4] = {av.x, av.y, av.z, av.w};
            float b_[4] = {bv.x, bv.y, bv.z, bv.w};
#pragma unroll
            for (int i = 0; i < 4; ++i)
#pragma unroll
                for (int j = 0; j < 4; ++j)
                    acc[i][j] = fmaf(a_[i], b_[j], acc[i][j]);
        }
    }
#pragma unroll
    for (int i = 0; i < 4; ++i) {
        const int r = row0 + ty * 4 + i;
        if (r < N_NODES) {
            const float s = dinv[r];
            float4 v = make_float4(acc[i][0] * s, acc[i][1] * s, acc[i][2] * s, acc[i][3] * s);
            *(float4*)(out + (size_t)r * HID_DIM + col0 + tx * 4) = v;
        }
    }
}

// ---------------- CSR aggregation, epilogue fused ----------------
// One 32-lane group per node: acc = sum(tab[src]); own = tab[node]; s = dinv[node].
// RELU=1: out = relu(s*(acc+own)+bias)*s   (layer-1, pre-scaled for layer-2)
// RELU=0: out = s*(acc+own)                (layer-2 pre-GEMM A2)
template <int RELU>
__global__ __launch_bounds__(256) void k_agg_csr(const float* __restrict__ tab,
                                                 const int* __restrict__ rp,
                                                 const int* __restrict__ ss,
                                                 const float* __restrict__ dinv,
                                                 const float* __restrict__ bias,
                                                 float* __restrict__ outp, int n) {
    int t = blockIdx.x * 256 + threadIdx.x;
    int node = t >> 5;
    int q = (t & 31) * 4;
    if (node >= n) return;
    int beg = rp[node], end = rp[node + 1];
    float ax = 0.f, ay = 0.f, az = 0.f, aw = 0.f;
    int i = beg;
    for (; i + 2 <= end; i += 2) {
        int s0 = ss[i], s1 = ss[i + 1];
        float4 v0 = *(const float4*)(tab + (size_t)s0 * HID_DIM + q);
        float4 v1 = *(const float4*)(tab + (size_t)s1 * HID_DIM + q);
        ax += v0.x + v1.x;
        ay += v0.y + v1.y;
        az += v0.z + v1.z;
        aw += v0.w + v1.w;
    }
    if (i < end) {
        int s0 = ss[i];
        float4 v0 = *(const float4*)(tab + (size_t)s0 * HID_DIM + q);
        ax += v0.x; ay += v0.y; az += v0.z; aw += v0.w;
    }
    float4 own = *(const float4*)(tab + (size_t)node * HID_DIM + q);
    float s = dinv[node];
    float4 r;
    if (RELU) {
        float4 bb = *(const float4*)(bias + q);
        r.x = fmaxf(fmaf(s, ax + own.x, bb.x), 0.f) * s;
        r.y = fmaxf(fmaf(s, ay + own.y, bb.y), 0.f) * s;
        r.z = fmaxf(fmaf(s, az + own.z, bb.z), 0.f) * s;
        r.w = fmaxf(fmaf(s, aw + own.w, bb.w), 0.f) * s;
    } else {
        r.x = s * (ax + own.x);
        r.y = s * (ay + own.y);
        r.z = s * (az + own.z);
        r.w = s * (aw + own.w);
    }
    *(float4*)(outp + (size_t)node * HID_DIM + q) = r;
}

// ---------------- GEMM2: out = A2 @ W2 + b2 ----------------
__global__ __launch_bounds__(256) void k_gemm2(const float* __restrict__ A2,
                                               const float* __restrict__ W2,
                                               const float* __restrict__ b2,
                                               float* __restrict__ out) {
    __shared__ float As[16 * 68];
    __shared__ float Bs[16 * 64];
    const int tid = threadIdx.x;
    const int tx = tid & 15, ty = tid >> 4;
    const int row0 = blockIdx.x * 64;
    const int col0 = blockIdx.y * 64;

    const int ar = tid >> 2;
    const int ak = (tid & 3) * 4;
    const int bk = tid >> 4;
    const int bc = (tid & 15) * 4;

    float acc[4][4] = {};

    for (int k0 = 0; k0 < HID_DIM; k0 += 16) {
        float4 a4 = make_float4(0.f, 0.f, 0.f, 0.f);
        const int grow = row0 + ar;
        if (grow < N_NODES) a4 = *(const float4*)(A2 + (size_t)grow * HID_DIM + k0 + ak);
        float bv[4];
#pragma unroll
        for (int j = 0; j < 4; ++j) {
            int c = col0 + bc + j;
            bv[j] = (c < OUT_DIM) ? W2[(size_t)(k0 + bk) * OUT_DIM + c] : 0.f;
        }
        __syncthreads();
        As[(ak + 0) * 68 + ar] = a4.x;
        As[(ak + 1) * 68 + ar] = a4.y;
        As[(ak + 2) * 68 + ar] = a4.z;
        As[(ak + 3) * 68 + ar] = a4.w;
        Bs[bk * 64 + bc + 0] = bv[0];
        Bs[bk * 64 + bc + 1] = bv[1];
        Bs[bk * 64 + bc + 2] = bv[2];
        Bs[bk * 64 + bc + 3] = bv[3];
        __syncthreads();
#pragma unroll
        for (int kk = 0; kk < 16; ++kk) {
            float4 av = *(const float4*)(As + kk * 68 + ty * 4);
            float4 bv4 = *(const float4*)(Bs + kk * 64 + tx * 4);
            float a_[4] = {av.x, av.y, av.z, av.w};
            float b_[4] = {bv4.x, bv4.y, bv4.z, bv4.w};
#pragma unroll
            for (int i = 0; i < 4; ++i)
#pragma unroll
                for (int j = 0; j < 4; ++j)
                    acc[i][j] = fmaf(a_[i], b_[j], acc[i][j]);
        }
    }
#pragma unroll
    for (int i = 0; i < 4; ++i) {
        const int r = row0 + ty * 4 + i;
        if (r < N_NODES) {
#pragma unroll
            for (int j = 0; j < 4; ++j) {
                int c = col0 + tx * 4 + j;
                if (c < OUT_DIM) out[(size_t)r * OUT_DIM + c] = acc[i][j] + b2[c];
            }
        }
    }
}

extern "C" void kernel_launch(void* const* d_in, const int* in_sizes, int n_in,
                              void* d_out, int out_size, void* d_ws, size_t ws_size,
                              hipStream_t stream) {
    const float* x  = (const float*)d_in[0];
    const int*   ei = (const int*)d_in[1];
    const float* W1 = (const float*)d_in[2];
    const float* b1 = (const float*)d_in[3];
    const float* W2 = (const float*)d_in[4];
    const float* b2 = (const float*)d_in[5];
    float* out = (float*)d_out;

    const int E = in_sizes[1] / 2;
    const int* src = ei;
    const int* dst = ei + E;

    // ws: hs (layer-1 scaled features), later reused as A2. 51.2 MB.
    float* hs = (float*)d_ws;
    float* A2 = hs;  // alias; hs dead before A2 written (stream order)

    // d_out hosts scratch until GEMM2 (final writer) runs:
    //   [0, 51.2MB)   h2  (layer-1 output, pre-scaled by dinv)
    //   then dinv, cnt/fill, row_ptr, bsum, src_sorted  (all dead before GEMM2)
    char* ob = (char*)d_out;
    size_t o = (size_t)N_NODES * HID_DIM * 4;      // 51,200,000
    float* h2 = (float*)ob;
    float* dinv = (float*)(ob + o); o += 400128;   // N*4 padded
    int* cnt = (int*)(ob + o); o += 400128;        // also scatter cursors (fill)
    int* rp  = (int*)(ob + o); o += 400384;        // (N+1)*4 padded
    int* bsum = (int*)(ob + o); o += 1024;         // 128 ints
    int* ss  = (int*)(ob + o);                     // E*4 = 6.4 MB

    const int NB = (N_NODES + 1023) / 1024;        // 98 scan blocks

    hipMemsetAsync(cnt, 0, (size_t)N_NODES * 4, stream);
    k_deg<<<(E + 255) / 256, 256, 0, stream>>>(dst, cnt, E);
    k_dinv<<<(N_NODES + 255) / 256, 256, 0, stream>>>(cnt, dinv, N_NODES);
    k_scan1<<<NB, 256, 0, stream>>>(cnt, rp, bsum, N_NODES);
    k_scan2<<<1, 128, 0, stream>>>(bsum, NB);
    k_scan3<<<NB, 256, 0, stream>>>(rp, cnt, bsum, N_NODES, E);  // cnt becomes fill
    k_scatter<<<(E + 255) / 256, 256, 0, stream>>>(src, dst, cnt, ss, E);

    dim3 g1((N_NODES + 63) / 64, HID_DIM / 64);
    k_gemm1<<<g1, 256, 0, stream>>>(x, W1, dinv, hs);

    const int aggBlocks = (N_NODES * 32 + 255) / 256;
    k_agg_csr<1><<<aggBlocks, 256, 0, stream>>>(hs, rp, ss, dinv, b1, h2, N_NODES);
    k_agg_csr<0><<<aggBlocks, 256, 0, stream>>>(h2, rp, ss, dinv, b1, A2, N_NODES);

    dim3 g2((N_NODES + 63) / 64, (OUT_DIM + 63) / 64);
    k_gemm2<<<g2, 256, 0, stream>>>(A2, W2, b2, out);
}

// Round 4
// 722.282 us; speedup vs baseline: 8.1292x; 1.0814x over previous
//
#include <hip/hip_runtime.h>

#define N_NODES 100000
#define IN_DIM  256
#define HID_DIM 128
#define OUT_DIM 237

#define BSH   9                      // bucket = dst >> 9  (512 nodes/bucket)
#define NBKT  196                    // ceil(100000 / 512)
#define BNODE 512

// ---------------- degree histogram + coarse bucket histogram ----------------
__global__ __launch_bounds__(256) void k_deg(const int* __restrict__ dst, int* __restrict__ cnt,
                                             int* __restrict__ bcnt, int E) {
    __shared__ int h[NBKT];
    for (int i = threadIdx.x; i < NBKT; i += 256) h[i] = 0;
    __syncthreads();
    const int base = blockIdx.x * 8192;
    for (int it = 0; it < 32; ++it) {
        int e = base + it * 256 + threadIdx.x;
        if (e < E) {
            int d = dst[e];
            atomicAdd(&cnt[d], 1);
            atomicAdd(&h[d >> BSH], 1);
        }
    }
    __syncthreads();
    for (int i = threadIdx.x; i < NBKT; i += 256)
        if (h[i]) atomicAdd(&bcnt[i], h[i]);
}

__global__ void k_dinv(const int* __restrict__ cnt, float* __restrict__ dinv, int n) {
    int i = blockIdx.x * 256 + threadIdx.x;
    if (i < n) dinv[i] = rsqrtf((float)cnt[i] + 1.0f);  // +1 self-loop
}

// ---------------- 2-level exclusive scan over cnt[0..n) -> rp ----------------
__global__ __launch_bounds__(256) void k_scan1(const int* __restrict__ cnt,
                                               int* __restrict__ rp,
                                               int* __restrict__ bsum, int n) {
    __shared__ int lds[256];
    const int tid = threadIdx.x;
    const int base = blockIdx.x * 1024 + tid * 4;
    int v[4];
#pragma unroll
    for (int j = 0; j < 4; ++j) v[j] = (base + j < n) ? cnt[base + j] : 0;
    int s = v[0] + v[1] + v[2] + v[3];
    lds[tid] = s;
    __syncthreads();
    for (int off = 1; off < 256; off <<= 1) {
        int t = (tid >= off) ? lds[tid - off] : 0;
        __syncthreads();
        lds[tid] += t;
        __syncthreads();
    }
    int run = lds[tid] - s;
#pragma unroll
    for (int j = 0; j < 4; ++j) {
        if (base + j < n) rp[base + j] = run;
        run += v[j];
    }
    if (tid == 255) bsum[blockIdx.x] = lds[255];
}

__global__ void k_scan2(int* __restrict__ bsum, int nb) {
    __shared__ int lds[128];
    int tid = threadIdx.x;
    int v = (tid < nb) ? bsum[tid] : 0;
    lds[tid] = v;
    __syncthreads();
    for (int off = 1; off < 128; off <<= 1) {
        int t = (tid >= off) ? lds[tid - off] : 0;
        __syncthreads();
        lds[tid] += t;
        __syncthreads();
    }
    if (tid < nb) bsum[tid] = lds[tid] - v;
}

__global__ __launch_bounds__(256) void k_scan3(int* __restrict__ rp,
                                               const int* __restrict__ bsum, int n, int E) {
    const int tid = threadIdx.x;
    const int base = blockIdx.x * 1024 + tid * 4;
    const int add = bsum[blockIdx.x];
#pragma unroll
    for (int j = 0; j < 4; ++j) {
        int i = base + j;
        if (i < n) rp[i] += add;
    }
    if (blockIdx.x == 0 && tid == 0) rp[n] = E;
}

// exclusive scan of bucket counts (NBKT <= 256), single block
__global__ void k_bscan(const int* __restrict__ bcnt, int* __restrict__ gbase,
                        int* __restrict__ gcur, int E) {
    __shared__ int lds[256];
    int tid = threadIdx.x;
    int v = (tid < NBKT) ? bcnt[tid] : 0;
    lds[tid] = v;
    __syncthreads();
    for (int off = 1; off < 256; off <<= 1) {
        int t = (tid >= off) ? lds[tid - off] : 0;
        __syncthreads();
        lds[tid] += t;
        __syncthreads();
    }
    int excl = lds[tid] - v;
    if (tid < NBKT) { gbase[tid] = excl; gcur[tid] = excl; }
    if (tid == 0) gbase[NBKT] = E;
}

// ---------------- pass 1: partition (src,dst) pairs into coarse buckets ----------------
__global__ __launch_bounds__(256) void k_part1(const int* __restrict__ src,
                                               const int* __restrict__ dst,
                                               int* __restrict__ gcur,
                                               int2* __restrict__ pairs, int E) {
    __shared__ int h[NBKT];
    __shared__ int base[NBKT];
    const int tid = threadIdx.x;
    for (int i = tid; i < NBKT; i += 256) h[i] = 0;
    __syncthreads();
    const int cbase = blockIdx.x * 8192;
    for (int it = 0; it < 32; ++it) {
        int e = cbase + it * 256 + tid;
        if (e < E) atomicAdd(&h[dst[e] >> BSH], 1);
    }
    __syncthreads();
    for (int i = tid; i < NBKT; i += 256) {
        int c = h[i];
        base[i] = c ? atomicAdd(&gcur[i], c) : 0;
    }
    __syncthreads();
    for (int i = tid; i < NBKT; i += 256) h[i] = 0;
    __syncthreads();
    for (int it = 0; it < 32; ++it) {
        int e = cbase + it * 256 + tid;
        if (e < E) {
            int d = dst[e];
            int b = d >> BSH;
            int pos = base[b] + atomicAdd(&h[b], 1);
            pairs[pos] = make_int2(src[e], d);
        }
    }
}

// ---------------- pass 2: within-bucket scatter with LDS cursors ----------------
__global__ __launch_bounds__(256) void k_part2(const int2* __restrict__ pairs,
                                               const int* __restrict__ gbase,
                                               const int* __restrict__ rp,
                                               int* __restrict__ ss, int n) {
    __shared__ int cur[BNODE];
    const int b = blockIdx.x;
    const int n0 = b << BSH;
    const int tid = threadIdx.x;
    for (int i = tid; i < BNODE; i += 256) {
        int node = n0 + i;
        cur[i] = (node < n) ? rp[node] : 0;
    }
    __syncthreads();
    const int beg = gbase[b], end = gbase[b + 1];
    for (int i = beg + tid; i < end; i += 256) {
        int2 p = pairs[i];
        int pos = atomicAdd(&cur[p.y - n0], 1);
        ss[pos] = p.x;
    }
}

// ---------------- GEMM1: hs = (X @ W1) * dinv[row], 128x128 tile, 8x8 micro ----------------
__global__ __launch_bounds__(256) void k_gemm1(const float* __restrict__ X,
                                               const float* __restrict__ W,
                                               const float* __restrict__ dinv,
                                               float* __restrict__ out) {
    __shared__ float As[16 * 132];   // [k][row], stride 132
    __shared__ float Bs[16 * 128];   // [k][col]
    const int tid = threadIdx.x;
    const int tx = tid & 15, ty = tid >> 4;
    const int row0 = blockIdx.x * 128;

    const int ar = tid >> 2;          // 0..63 (two halves: +0, +64)
    const int ak = (tid & 3) * 4;     // k offset
    const int bk = tid >> 5;          // 0..7 (two halves: +0, +8)
    const int bc = (tid & 31) * 4;    // col offset

    float acc[8][8] = {};

    for (int k0 = 0; k0 < IN_DIM; k0 += 16) {
        float4 a0 = make_float4(0.f, 0.f, 0.f, 0.f), a1 = a0;
        const int r0 = row0 + ar, r1 = row0 + ar + 64;
        if (r0 < N_NODES) a0 = *(const float4*)(X + (size_t)r0 * IN_DIM + k0 + ak);
        if (r1 < N_NODES) a1 = *(const float4*)(X + (size_t)r1 * IN_DIM + k0 + ak);
        float4 b0 = *(const float4*)(W + (size_t)(k0 + bk) * HID_DIM + bc);
        float4 b1 = *(const float4*)(W + (size_t)(k0 + bk + 8) * HID_DIM + bc);
        __syncthreads();
        As[(ak + 0) * 132 + ar] = a0.x;
        As[(ak + 1) * 132 + ar] = a0.y;
        As[(ak + 2) * 132 + ar] = a0.z;
        As[(ak + 3) * 132 + ar] = a0.w;
        As[(ak + 0) * 132 + ar + 64] = a1.x;
        As[(ak + 1) * 132 + ar + 64] = a1.y;
        As[(ak + 2) * 132 + ar + 64] = a1.z;
        As[(ak + 3) * 132 + ar + 64] = a1.w;
        *(float4*)(Bs + bk * 128 + bc) = b0;
        *(float4*)(Bs + (bk + 8) * 128 + bc) = b1;
        __syncthreads();
#pragma unroll
        for (int kk = 0; kk < 16; ++kk) {
            float4 A0 = *(const float4*)(As + kk * 132 + ty * 4);
            float4 A1 = *(const float4*)(As + kk * 132 + 64 + ty * 4);
            float4 B0 = *(const float4*)(Bs + kk * 128 + tx * 4);
            float4 B1 = *(const float4*)(Bs + kk * 128 + 64 + tx * 4);
            float a_[8] = {A0.x, A0.y, A0.z, A0.w, A1.x, A1.y, A1.z, A1.w};
            float b_[8] = {B0.x, B0.y, B0.z, B0.w, B1.x, B1.y, B1.z, B1.w};
#pragma unroll
            for (int i = 0; i < 8; ++i)
#pragma unroll
                for (int j = 0; j < 8; ++j)
                    acc[i][j] = fmaf(a_[i], b_[j], acc[i][j]);
        }
    }
#pragma unroll
    for (int i = 0; i < 8; ++i) {
        const int r = row0 + ty * 4 + (i & 3) + (i >> 2) * 64;
        if (r < N_NODES) {
            const float s = dinv[r];
            float4 v0 = make_float4(acc[i][0] * s, acc[i][1] * s, acc[i][2] * s, acc[i][3] * s);
            float4 v1 = make_float4(acc[i][4] * s, acc[i][5] * s, acc[i][6] * s, acc[i][7] * s);
            *(float4*)(out + (size_t)r * HID_DIM + tx * 4) = v0;
            *(float4*)(out + (size_t)r * HID_DIM + 64 + tx * 4) = v1;
        }
    }
}

// ---------------- CSR aggregation, epilogue fused ----------------
template <int RELU>
__global__ __launch_bounds__(256) void k_agg_csr(const float* __restrict__ tab,
                                                 const int* __restrict__ rp,
                                                 const int* __restrict__ ss,
                                                 const float* __restrict__ dinv,
                                                 const float* __restrict__ bias,
                                                 float* __restrict__ outp, int n) {
    int t = blockIdx.x * 256 + threadIdx.x;
    int node = t >> 5;
    int q = (t & 31) * 4;
    if (node >= n) return;
    int beg = rp[node], end = rp[node + 1];
    float ax = 0.f, ay = 0.f, az = 0.f, aw = 0.f;
    int i = beg;
    for (; i + 2 <= end; i += 2) {
        int s0 = ss[i], s1 = ss[i + 1];
        float4 v0 = *(const float4*)(tab + (size_t)s0 * HID_DIM + q);
        float4 v1 = *(const float4*)(tab + (size_t)s1 * HID_DIM + q);
        ax += v0.x + v1.x;
        ay += v0.y + v1.y;
        az += v0.z + v1.z;
        aw += v0.w + v1.w;
    }
    if (i < end) {
        int s0 = ss[i];
        float4 v0 = *(const float4*)(tab + (size_t)s0 * HID_DIM + q);
        ax += v0.x; ay += v0.y; az += v0.z; aw += v0.w;
    }
    float4 own = *(const float4*)(tab + (size_t)node * HID_DIM + q);
    float s = dinv[node];
    float4 r;
    if (RELU) {
        float4 bb = *(const float4*)(bias + q);
        r.x = fmaxf(fmaf(s, ax + own.x, bb.x), 0.f) * s;
        r.y = fmaxf(fmaf(s, ay + own.y, bb.y), 0.f) * s;
        r.z = fmaxf(fmaf(s, az + own.z, bb.z), 0.f) * s;
        r.w = fmaxf(fmaf(s, aw + own.w, bb.w), 0.f) * s;
    } else {
        r.x = s * (ax + own.x);
        r.y = s * (ay + own.y);
        r.z = s * (az + own.z);
        r.w = s * (aw + own.w);
    }
    *(float4*)(outp + (size_t)node * HID_DIM + q) = r;
}

// ---------------- GEMM2: out = A2 @ W2 + b2, 128x128 tile, 8x8 micro ----------------
__global__ __launch_bounds__(256) void k_gemm2(const float* __restrict__ A2,
                                               const float* __restrict__ W2,
                                               const float* __restrict__ b2,
                                               float* __restrict__ out) {
    __shared__ float As[16 * 132];
    __shared__ float Bs[16 * 128];
    const int tid = threadIdx.x;
    const int tx = tid & 15, ty = tid >> 4;
    const int row0 = blockIdx.x * 128;
    const int col0 = blockIdx.y * 128;

    const int ar = tid >> 2;
    const int ak = (tid & 3) * 4;
    const int bk = tid >> 5;
    const int bc = (tid & 31) * 4;

    float acc[8][8] = {};

    for (int k0 = 0; k0 < HID_DIM; k0 += 16) {
        float4 a0 = make_float4(0.f, 0.f, 0.f, 0.f), a1 = a0;
        const int r0 = row0 + ar, r1 = row0 + ar + 64;
        if (r0 < N_NODES) a0 = *(const float4*)(A2 + (size_t)r0 * HID_DIM + k0 + ak);
        if (r1 < N_NODES) a1 = *(const float4*)(A2 + (size_t)r1 * HID_DIM + k0 + ak);
        float bv0[4], bv1[4];
#pragma unroll
        for (int j = 0; j < 4; ++j) {
            int c = col0 + bc + j;
            bv0[j] = (c < OUT_DIM) ? W2[(size_t)(k0 + bk) * OUT_DIM + c] : 0.f;
            bv1[j] = (c < OUT_DIM) ? W2[(size_t)(k0 + bk + 8) * OUT_DIM + c] : 0.f;
        }
        __syncthreads();
        As[(ak + 0) * 132 + ar] = a0.x;
        As[(ak + 1) * 132 + ar] = a0.y;
        As[(ak + 2) * 132 + ar] = a0.z;
        As[(ak + 3) * 132 + ar] = a0.w;
        As[(ak + 0) * 132 + ar + 64] = a1.x;
        As[(ak + 1) * 132 + ar + 64] = a1.y;
        As[(ak + 2) * 132 + ar + 64] = a1.z;
        As[(ak + 3) * 132 + ar + 64] = a1.w;
#pragma unroll
        for (int j = 0; j < 4; ++j) {
            Bs[bk * 128 + bc + j] = bv0[j];
            Bs[(bk + 8) * 128 + bc + j] = bv1[j];
        }
        __syncthreads();
#pragma unroll
        for (int kk = 0; kk < 16; ++kk) {
            float4 A0 = *(const float4*)(As + kk * 132 + ty * 4);
            float4 A1 = *(const float4*)(As + kk * 132 + 64 + ty * 4);
            float4 B0 = *(const float4*)(Bs + kk * 128 + tx * 4);
            float4 B1 = *(const float4*)(Bs + kk * 128 + 64 + tx * 4);
            float a_[8] = {A0.x, A0.y, A0.z, A0.w, A1.x, A1.y, A1.z, A1.w};
            float b_[8] = {B0.x, B0.y, B0.z, B0.w, B1.x, B1.y, B1.z, B1.w};
#pragma unroll
            for (int i = 0; i < 8; ++i)
#pragma unroll
                for (int j = 0; j < 8; ++j)
                    acc[i][j] = fmaf(a_[i], b_[j], acc[i][j]);
        }
    }
#pragma unroll
    for (int i = 0; i < 8; ++i) {
        const int r = row0 + ty * 4 + (i & 3) + (i >> 2) * 64;
        if (r < N_NODES) {
#pragma unroll
            for (int j = 0; j < 8; ++j) {
                int c = col0 + tx * 4 + (j & 3) + (j >> 2) * 64;
                if (c < OUT_DIM) out[(size_t)r * OUT_DIM + c] = acc[i][j] + b2[c];
            }
        }
    }
}

extern "C" void kernel_launch(void* const* d_in, const int* in_sizes, int n_in,
                              void* d_out, int out_size, void* d_ws, size_t ws_size,
                              hipStream_t stream) {
    const float* x  = (const float*)d_in[0];
    const int*   ei = (const int*)d_in[1];
    const float* W1 = (const float*)d_in[2];
    const float* b1 = (const float*)d_in[3];
    const float* W2 = (const float*)d_in[4];
    const float* b2 = (const float*)d_in[5];
    float* out = (float*)d_out;

    const int E = in_sizes[1] / 2;
    const int* src = ei;
    const int* dst = ei + E;

    // ws: hs (layer-1 scaled features) / A2 alias. 51.2 MB.
    float* hs = (float*)d_ws;
    float* A2 = hs;

    // d_out scratch (all dead before k_gemm2, the sole final writer):
    char* ob = (char*)d_out;
    size_t o = (size_t)N_NODES * HID_DIM * 4;          // h2: 51.2 MB
    float* h2 = (float*)ob;
    float* dinv = (float*)(ob + o); o += 400128;
    int* cnt  = (int*)(ob + o); o += 400128;
    int* bcnt = (int*)(ob + o); o += 1024;             // NBKT ints (memset with cnt)
    int* rp   = (int*)(ob + o); o += 400640;           // (N+1) ints padded
    int* bsum = (int*)(ob + o); o += 1024;             // 98 ints
    int* gbase = (int*)(ob + o); o += 1024;            // NBKT+1 ints
    int* gcur  = (int*)(ob + o); o += 1024;
    int* ss   = (int*)(ob + o); o += (size_t)E * 4;    // 6.4 MB
    int2* pairs = (int2*)(ob + o);                     // 12.8 MB

    const int NB  = (N_NODES + 1023) / 1024;           // 98
    const int NB1 = (E + 8191) / 8192;                 // 196

    hipMemsetAsync(cnt, 0, 400128 + 1024, stream);     // cnt + bcnt (adjacent)
    k_deg<<<NB1, 256, 0, stream>>>(dst, cnt, bcnt, E);
    k_dinv<<<(N_NODES + 255) / 256, 256, 0, stream>>>(cnt, dinv, N_NODES);
    k_scan1<<<NB, 256, 0, stream>>>(cnt, rp, bsum, N_NODES);
    k_scan2<<<1, 128, 0, stream>>>(bsum, NB);
    k_scan3<<<NB, 256, 0, stream>>>(rp, bsum, N_NODES, E);
    k_bscan<<<1, 256, 0, stream>>>(bcnt, gbase, gcur, E);
    k_part1<<<NB1, 256, 0, stream>>>(src, dst, gcur, pairs, E);
    k_part2<<<NBKT, 256, 0, stream>>>(pairs, gbase, rp, ss, N_NODES);

    dim3 g1((N_NODES + 127) / 128, 1);
    k_gemm1<<<g1, 256, 0, stream>>>(x, W1, dinv, hs);

    const int aggBlocks = (N_NODES * 32 + 255) / 256;
    k_agg_csr<1><<<aggBlocks, 256, 0, stream>>>(hs, rp, ss, dinv, b1, h2, N_NODES);
    k_agg_csr<0><<<aggBlocks, 256, 0, stream>>>(h2, rp, ss, dinv, b1, A2, N_NODES);

    dim3 g2((N_NODES + 127) / 128, (OUT_DIM + 127) / 128);
    k_gemm2<<<g2, 256, 0, stream>>>(A2, W2, b2, out);
}